// Round 19
// baseline (121.539 us; speedup 1.0000x reference)
//
#include <hip/hip_runtime.h>
#include <hip/hip_bf16.h>
#include <stdint.h>

#define NB 2
#define NS 2048
#define NE 1024
#define NH 16
#define ND 64
#define N3 3072

typedef __attribute__((ext_vector_type(8))) short s16x8;
typedef __attribute__((ext_vector_type(4))) short s16x4;
typedef __attribute__((ext_vector_type(4))) float f32x4;
typedef __attribute__((ext_vector_type(16))) float f32x16;
typedef __attribute__((ext_vector_type(2))) unsigned int u32x2;
typedef __attribute__((ext_vector_type(4))) unsigned int u32x4;

__device__ __forceinline__ float bf2f(short u){
  union { unsigned int i; float f; } v; v.i = ((unsigned int)(unsigned short)u) << 16; return v.f;
}
__device__ __forceinline__ short f2bf(float f){
  union { __hip_bfloat16 h; short s; } v; v.h = __float2bfloat16(f); return v.s;
}
__device__ __forceinline__ f32x4 mfma16(s16x8 a, s16x8 b, f32x4 c){
  return __builtin_amdgcn_mfma_f32_16x16x32_bf16(a, b, c, 0, 0, 0);
}
__device__ __forceinline__ f32x16 mfma32(s16x8 a, s16x8 b, f32x16 c){
  return __builtin_amdgcn_mfma_f32_32x32x16_bf16(a, b, c, 0, 0, 0);
}
__device__ __forceinline__ void load_lds16(const void* g, void* l){
  __builtin_amdgcn_global_load_lds(
      (const __attribute__((address_space(1))) unsigned int*)g,
      (__attribute__((address_space(3))) unsigned int*)l, 16, 0, 0);
}
__device__ __forceinline__ unsigned int cvtpk_bf16(float lo, float hi){
  unsigned int d;
  asm("v_cvt_pk_bf16_f32 %0, %1, %2" : "=v"(d) : "v"(lo), "v"(hi));
  return d;
}
// 64-lane reductions via permlane32 swap (VALU, no LDS pipe)
__device__ __forceinline__ float redmax64(float v){
  u32x2 b = __builtin_amdgcn_permlane32_swap(__float_as_uint(v), __float_as_uint(v), false, false);
  return fmaxf(__uint_as_float(b[0]), __uint_as_float(b[1]));
}
__device__ __forceinline__ float redsum64(float v){
  u32x2 b = __builtin_amdgcn_permlane32_swap(__float_as_uint(v), __float_as_uint(v), false, false);
  return __uint_as_float(b[0]) + __uint_as_float(b[1]);
}

// ---------------- merged pre-pass: x->bf16  +  w_qkv^T->bf16  +  w_o^T->bf16 ----------------
__global__ __launch_bounds__(256) void k_pre(const float* __restrict__ x,
    const float* __restrict__ w_qkv, const float* __restrict__ w_o,
    short* __restrict__ Xb, short* __restrict__ Wqkvt, short* __restrict__ Wot)
{
  __shared__ float t[32][33];
  const int bid = blockIdx.x, tid = threadIdx.x;
  if (bid < 4096){
    int i = bid * 256 + tid;
    float4 v = ((const float4*)x)[i];
    s16x4 o = { f2bf(v.x), f2bf(v.y), f2bf(v.z), f2bf(v.w) };
    *(s16x4*)(Xb + (size_t)i*4) = o;
    return;
  }
  const float* in; short* out; int R, C, tile;
  if (bid < 7168){ in = w_qkv; out = Wqkvt; R = NE; C = N3; tile = bid - 4096; }
  else           { in = w_o;   out = Wot;   R = NE; C = NE; tile = bid - 7168; }
  const int tc = C >> 5;
  int c0 = (tile % tc) * 32, r0 = (tile / tc) * 32;
  int tx = tid & 31, ty = tid >> 5;
  #pragma unroll
  for (int i=0;i<4;++i){
    int r = r0 + ty + i*8;
    t[ty + i*8][tx] = in[(size_t)r*C + c0 + tx];
  }
  __syncthreads();
  #pragma unroll
  for (int i=0;i<4;++i){
    int cc = c0 + ty + i*8;
    out[(size_t)cc*R + r0 + tx] = f2bf(t[tx][ty + i*8]);
  }
}

// ---------------- bf16 GEMM: C[M][N] = A[M][K] * Bt[N][K]^T + bias ----------------
// Double-buffered counted-vmcnt pipeline; XCD-aware column-major 1D chunking.
template<int OUTF32>
__global__ __launch_bounds__(256) void k_gemm(const short* __restrict__ A,
    const short* __restrict__ Bt, const float* __restrict__ bias,
    short* __restrict__ outB, float* __restrict__ outF, int M, int N, int K)
{
  __shared__ short lds[2][128*64*2];  // 64 KB: per buf, A tile [128][64] then B tile
  const int tid = threadIdx.x;
  const int lane = tid & 63, w = tid >> 6;
  const int g = lane >> 4, c = lane & 15;
  const int wm = (w >> 1) * 64, wn = (w & 1) * 64;
  const int T = gridDim.x;                 // total tiles, divisible by 8
  const int chunk = T >> 3;
  const int tile = (blockIdx.x & 7) * chunk + (blockIdx.x >> 3);
  const int tm = tile & 31;                // M/128 = 32 always here
  const int tn = tile >> 5;
  const int bm = tm * 128, bn = tn * 128;

  f32x4 acc[4][4];
  #pragma unroll
  for (int i=0;i<4;++i)
    #pragma unroll
    for (int j=0;j<4;++j) acc[i][j] = (f32x4){0.f,0.f,0.f,0.f};

  auto STAGE = [&](int kt, int bsel){
    #pragma unroll
    for (int i = 0; i < 8; ++i){
      const int seg   = w*8 + i;          // 0..31 ; segs 0-15 = A, 16-31 = B
      const int chunkc = seg*64 + lane;   // 16-byte units
      const int local = chunkc & 1023;
      const int row = local >> 3, kc = local & 7;
      const short* base = (chunkc < 1024)
        ? (A  + (size_t)(bm + row) * K + kt*64)
        : (Bt + (size_t)(bn + row) * K + kt*64);
      const char* gaddr = (const char*)base + ((kc*16) ^ ((row & 7) << 4));
      load_lds16(gaddr, (char*)&lds[bsel][0] + seg*1024);
    }
  };

  const int nkt = K >> 6;
  STAGE(0, 0);
  for (int kt = 0; kt < nkt; ++kt){
    const int cur = kt & 1;
    if (kt + 1 < nkt){
      STAGE(kt + 1, cur ^ 1);
      asm volatile("s_waitcnt vmcnt(8)" ::: "memory");  // stage(kt) retired, kt+1 in flight
    } else {
      asm volatile("s_waitcnt vmcnt(0)" ::: "memory");
    }
    __builtin_amdgcn_s_barrier();           // top: stage(kt) visible to all waves
    __builtin_amdgcn_sched_barrier(0);
    const char* Lc = (const char*)&lds[cur][0];
    #pragma unroll
    for (int kk = 0; kk < 2; ++kk){
      s16x8 af[4], bfr[4];
      #pragma unroll
      for (int mi = 0; mi < 4; ++mi){
        int m = wm + mi*16 + c;
        int kb = (kk*64 + g*16) ^ ((m & 7) << 4);
        af[mi] = *(const s16x8*)(Lc + m*128 + kb);
      }
      #pragma unroll
      for (int ni = 0; ni < 4; ++ni){
        int n = wn + ni*16 + c;
        int kb = (kk*64 + g*16) ^ ((n & 7) << 4);
        bfr[ni] = *(const s16x8*)(Lc + 16384 + n*128 + kb);
      }
      #pragma unroll
      for (int mi = 0; mi < 4; ++mi)
        #pragma unroll
        for (int ni = 0; ni < 4; ++ni)
          acc[mi][ni] = mfma16(af[mi], bfr[ni], acc[mi][ni]);
    }
    __builtin_amdgcn_sched_barrier(0);
    __builtin_amdgcn_s_barrier();           // bottom: all waves done with buf[cur]
  }
  #pragma unroll
  for (int mi = 0; mi < 4; ++mi){
    #pragma unroll
    for (int ni = 0; ni < 4; ++ni){
      int col = bn + wn + ni*16 + c;
      float bv = bias[col];
      #pragma unroll
      for (int j = 0; j < 4; ++j){
        int rrow = bm + wm + mi*16 + g*4 + j;   // C/D: col=lane&15, row=4*(lane>>4)+j
        float v = acc[mi][ni][j] + bv;
        if (OUTF32) outF[(size_t)rrow * N + col] = v;
        else        outB[(size_t)rrow * N + col] = f2bf(v);
      }
    }
  }
}

// ---------------- fused prep: Q/K-RoPE -> Qr,Kr [B,H,S,D]  +  V-transpose -> Vt ----
__global__ void k_prep(const short* __restrict__ qkv, short* __restrict__ Qr,
                       short* __restrict__ Kr, short* __restrict__ Vt){
  __shared__ short t[64][72];
  const int bid = blockIdx.x;                 // B*H*(S/64) = 1024
  const int sb = bid & 31, h = (bid>>5) & 15, b = bid >> 9;
  const int s0 = sb * 64;
  const int tid = threadIdx.x;
  const float LGI = 13.287712379549449f / 32.0f;   // log2(10000)/32
  const float QSC = 0.125f * 1.44269504088896340736f;
  #pragma unroll
  for (int it=0; it<2; ++it){
    int u = it*256 + tid;
    int r = u >> 3, cc = (u & 7) * 8;
    int s = s0 + r;
    size_t src = (size_t)(b*NS + s)*N3 + h*ND + cc;
    size_t dst = ((size_t)(b*NH + h)*NS + s)*ND + cc;
    s16x8 rq = *(const s16x8*)(qkv + src);
    s16x8 rk = *(const s16x8*)(qkv + src + 1024);
    s16x8 oq, ok;
    #pragma unroll
    for (int jp=0; jp<4; ++jp){
      int i = (cc >> 1) + jp;
      float inv = __builtin_amdgcn_exp2f(-(float)i * LGI);
      float ang = (float)s * inv;
      float cs = cosf(ang), sn = sinf(ang);
      float q0 = bf2f(rq[2*jp]), q1 = bf2f(rq[2*jp+1]);
      oq[2*jp]   = f2bf((q0*cs - q1*sn) * QSC);
      oq[2*jp+1] = f2bf((q1*cs + q0*sn) * QSC);
      float k0 = bf2f(rk[2*jp]), k1 = bf2f(rk[2*jp+1]);
      ok[2*jp]   = f2bf(k0*cs - k1*sn);
      ok[2*jp+1] = f2bf(k1*cs + k0*sn);
    }
    *(s16x8*)(Qr + dst) = oq;
    *(s16x8*)(Kr + dst) = ok;
  }
  #pragma unroll
  for (int it=0; it<2; ++it){
    int u = it*256 + tid;
    int r = u >> 3, cc = (u & 7) * 8;
    s16x8 v = *(const s16x8*)(qkv + (size_t)(b*NS + s0 + r)*N3 + 2048 + h*ND + cc);
    *(s16x8*)&t[r][cc] = v;
  }
  __syncthreads();
  #pragma unroll
  for (int it=0; it<2; ++it){
    int u = it*256 + tid;
    int d = u >> 3, sc2 = (u & 7) * 8;
    s16x8 v;
    #pragma unroll
    for (int j=0;j<8;++j) v[j] = t[sc2 + j][d];
    *(s16x8*)(Vt + ((size_t)(b*NH + h)*ND + d)*NS + s0 + sc2) = v;
  }
}

// ---------------- causal flash attention, SPLIT-K/2 (32x32 MFMA, in-register P) ----
// R12/R15's replay-proven body and two-barrier skeleton, parameterized by a
// K-tile range [t0,t1): sub 0 takes the first ceil(nkt/2) tiles, sub 1 the
// rest. 1024 blocks (2 per q-tile, same XCD as their sibling); each writes
// UNNORMALIZED bf16 partial O + per-row (lrow, mrow); k_comb merges. Empty
// ranges (qb=0 sub1) write (0, 0, -3e38) -> zero weight in the merge.
__global__ __launch_bounds__(256) void k_attn(const short* __restrict__ Qr,
    const short* __restrict__ Kr2, const short* __restrict__ Vt,
    short* __restrict__ Pacc, float* __restrict__ Lrow, float* __restrict__ Mrow)
{
  __shared__ short Kb[2][128*64];             // 32 KB  [k=128][d=64] rows 128B
  __shared__ short Vb[2][64*128];             // 32 KB  [d=64][k=128] rows 256B
  const int tid = threadIdx.x;
  const int lane = tid & 63, w = tid >> 6;
  const int ql = lane & 31, hi = lane >> 5;
  const int bid = blockIdx.x;                 // 1024
  const int sub = bid >> 9;                   // 0: first half of K, 1: second
  const int bb  = bid & 511;
  const int xcd = bb & 7;
  const int qq  = (bb >> 3) & 31;
  const int heavy = (bb < 256);
  const int j = qq >> 2;                      // 0..7
  const int qb = heavy ? (15 - j) : j;
  const int gid = xcd + 8*(qq & 3);           // (b,h), XCD-local (4 groups/XCD)
  const int h = gid & 15;
  const int b = gid >> 4;
  const int tl = gid*16 + qb;                 // canonical tile id 0..511
  const size_t bh = (size_t)(b*NH + h);
  const short* Qbh = Qr + bh * (NS*ND);
  const short* Kbh = Kr2 + bh * (NS*ND);
  const short* Vbh = Vt + bh * (ND*NS);

  // ---- hoisted per-lane staging sources (pre-swizzled) ----
  const char* pK0[4]; const char* pV0[4];
  #pragma unroll
  for (int i=0;i<4;++i){
    int u = w*256 + i*64 + lane;              // 16B-chunk id 0..1023
    int rk = u >> 3, kck = u & 7;             // K: 128 rows x 8 chunks
    pK0[i] = (const char*)Kbh + rk*128 + ((kck*16) ^ ((rk & 7) << 4));
    int rv = u >> 4, kcv = u & 15;            // V: 64 rows x 16 chunks
    pV0[i] = (const char*)Vbh + (size_t)rv*(NS*2) + ((kcv*16) ^ ((rv & 7) << 4));
  }
  int roffK[4][4];
  #pragma unroll
  for (int fr=0; fr<4; ++fr)
    #pragma unroll
    for (int dc=0; dc<4; ++dc){
      int row = fr*32 + ql;
      roffK[fr][dc] = row*128 + ((dc*32 + 16*hi) ^ ((row & 7) << 4));
    }
  int roffV[2][8];
  #pragma unroll
  for (int fr=0; fr<2; ++fr)
    #pragma unroll
    for (int kk=0; kk<8; ++kk){
      int row = fr*32 + ql;
      roffV[fr][kk] = row*256 + ((kk*32 + 16*hi) ^ ((row & 7) << 4));
    }

  auto STAGE = [&](int tt, int bsel){
    #pragma unroll
    for (int i=0;i<4;++i){
      load_lds16(pK0[i] + (size_t)tt*16384, (char*)&Kb[bsel][0] + w*4096 + i*1024);
      load_lds16(pV0[i] + (size_t)tt*256,   (char*)&Vb[bsel][0] + w*4096 + i*1024);
    }
  };

  const int q0 = qb*128 + w*32;
  const int qglob = q0 + ql;
  const int qtop = q0 + 31;
  const int nkt = qb + 1;
  const int hn = (nkt + 1) >> 1;
  const int t0 = sub ? hn : 0;
  const int t1 = sub ? nkt : hn;              // block-uniform range

  s16x8 qf[4];
  #pragma unroll
  for (int dc=0; dc<4; ++dc)
    qf[dc] = *(const s16x8*)(Qbh + (size_t)(q0 + ql)*ND + dc*16 + 8*hi);
  f32x16 accA, accB;
  #pragma unroll
  for (int r=0;r<16;++r){ accA[r]=0.f; accB[r]=0.f; }
  float mrow = -3.0e38f, lrow = 0.f;

  if (t0 < t1) STAGE(t0, t0 & 1);
  for (int t = t0; t < t1; ++t){
    const int cur = t & 1;
    if (t + 1 < t1){
      STAGE(t + 1, cur ^ 1);
      asm volatile("s_waitcnt vmcnt(8)" ::: "memory");  // stage(t) retired, t+1 in flight
    } else {
      asm volatile("s_waitcnt vmcnt(0)" ::: "memory");
    }
    __builtin_amdgcn_s_barrier();             // top: stage(t) visible to all waves
    __builtin_amdgcn_sched_barrier(0);
    if (t*128 <= qtop){                       // conditional body (uniform barriers)
      const char* Kc = (const char*)&Kb[cur][0];
      const char* Vc = (const char*)&Vb[cur][0];
      // ---- QK^T: S^T[k][q], k-quarters fr=0..3 ----
      f32x16 st[4];
      #pragma unroll
      for (int fr=0; fr<4; ++fr)
        #pragma unroll
        for (int r=0;r<16;++r) st[fr][r]=0.f;
      __builtin_amdgcn_s_setprio(1);
      #pragma unroll
      for (int dc=0; dc<4; ++dc)
        #pragma unroll
        for (int fr=0; fr<4; ++fr){
          s16x8 ka = *(const s16x8*)(Kc + roffK[fr][dc]);
          st[fr] = mfma32(ka, qf[dc], st[fr]);
        }
      __builtin_amdgcn_s_setprio(0);
      // ---- causal mask (only tiles overlapping the wave's diagonal) ----
      if (t*128 + 127 > q0){
        #pragma unroll
        for (int fr=0; fr<4; ++fr)
          #pragma unroll
          for (int r=0; r<16; ++r){
            int kg = t*128 + fr*32 + (r&3) + 8*(r>>2) + 4*hi;
            if (kg > qglob) st[fr][r] = -3.0e38f;
          }
      }
      // ---- online softmax (exp2 domain; q = lane&31 lane-local) ----
      float mm[8];
      #pragma unroll
      for (int r=0; r<8; ++r)
        mm[r] = fmaxf(fmaxf(st[0][r], st[0][r+8]), fmaxf(st[1][r], st[1][r+8]));
      #pragma unroll
      for (int r=0; r<8; ++r)
        mm[r] = fmaxf(mm[r], fmaxf(fmaxf(st[2][r], st[2][r+8]),
                                   fmaxf(st[3][r], st[3][r+8])));
      float tm = fmaxf(fmaxf(fmaxf(mm[0],mm[1]), fmaxf(mm[2],mm[3])),
                       fmaxf(fmaxf(mm[4],mm[5]), fmaxf(mm[6],mm[7])));
      tm = redmax64(tm);
      float mn = fmaxf(mrow, tm);
      #pragma unroll
      for (int fr=0; fr<4; ++fr)
        #pragma unroll
        for (int r=0; r<16; ++r)
          st[fr][r] = __builtin_amdgcn_exp2f(st[fr][r] - mn);
      float ss[8];
      #pragma unroll
      for (int r=0; r<8; ++r)
        ss[r] = ((st[0][r] + st[0][r+8]) + (st[1][r] + st[1][r+8]))
              + ((st[2][r] + st[2][r+8]) + (st[3][r] + st[3][r+8]));
      float tl2 = ((ss[0]+ss[1]) + (ss[2]+ss[3])) + ((ss[4]+ss[5]) + (ss[6]+ss[7]));
      tl2 = redsum64(tl2);
      float alpha = __builtin_amdgcn_exp2f(mrow - mn);
      lrow = lrow*alpha + tl2;
      mrow = mn;
      #pragma unroll
      for (int r=0; r<16; ++r){ accA[r] *= alpha; accB[r] *= alpha; }
      // ---- P -> PV B-fragments, fully in-register (cvt_pk + permlane32_swap) ----
      s16x8 pa[8];
      #pragma unroll
      for (int kk=0; kk<8; ++kk){
        const int fr = kk >> 1, m = kk & 1;
        unsigned int P0 = cvtpk_bf16(st[fr][8*m+0], st[fr][8*m+1]);
        unsigned int P1 = cvtpk_bf16(st[fr][8*m+2], st[fr][8*m+3]);
        unsigned int P2 = cvtpk_bf16(st[fr][8*m+4], st[fr][8*m+5]);
        unsigned int P3 = cvtpk_bf16(st[fr][8*m+6], st[fr][8*m+7]);
        u32x2 s02 = __builtin_amdgcn_permlane32_swap(P0, P2, false, false);
        u32x2 s13 = __builtin_amdgcn_permlane32_swap(P1, P3, false, false);
        u32x4 pd = { s02[0], s13[0], s02[1], s13[1] };
        pa[kk] = *(s16x8*)&pd;
      }
      // ---- PV: O^T[d][q] += V^T[d][k] * P[k][q] ----
      __builtin_amdgcn_s_setprio(1);
      #pragma unroll
      for (int kk=0; kk<8; ++kk){
        s16x8 va  = *(const s16x8*)(Vc + roffV[0][kk]);
        s16x8 vb2 = *(const s16x8*)(Vc + roffV[1][kk]);
        accA = mfma32(va,  pa[kk], accA);
        accB = mfma32(vb2, pa[kk], accB);
      }
      __builtin_amdgcn_s_setprio(0);
    }
    __builtin_amdgcn_sched_barrier(0);
    __builtin_amdgcn_s_barrier();             // bottom: all waves done with buf[cur]
  }
  // ---- write unnormalized partials ----
  const int prow = ((sub << 9) + tl)*128 + w*32 + ql;
  short* pb = Pacc + (size_t)prow * 64;
  #pragma unroll
  for (int f=0; f<4; ++f){
    s16x4 oa = { f2bf(accA[4*f+0]), f2bf(accA[4*f+1]),
                 f2bf(accA[4*f+2]), f2bf(accA[4*f+3]) };
    *(s16x4*)(pb + 8*f + 4*hi) = oa;
    s16x4 ob = { f2bf(accB[4*f+0]), f2bf(accB[4*f+1]),
                 f2bf(accB[4*f+2]), f2bf(accB[4*f+3]) };
    *(s16x4*)(pb + 32 + 8*f + 4*hi) = ob;
  }
  if (hi == 0){
    Lrow[prow] = lrow;
    Mrow[prow] = mrow;
  }
}

// ---------------- split-K combine: O = (a1*w1 + a2*w2) / (l1*w1 + l2*w2) ----------------
__global__ __launch_bounds__(256) void k_comb(const short* __restrict__ Pacc,
    const float* __restrict__ Lrow, const float* __restrict__ Mrow,
    short* __restrict__ Out)
{
  const int tl = blockIdx.x;                  // 512 tiles
  const int tid = threadIdx.x;
  const int gid = tl >> 4, qb = tl & 15;
  const int h = gid & 15, b = gid >> 4;
  const int q = tid >> 1;                     // 0..127
  const int d0 = (tid & 1) * 32;
  const int i1 = tl*128 + q;
  const int i2 = (512 + tl)*128 + q;
  float l1 = Lrow[i1], m1 = Mrow[i1];
  float l2 = Lrow[i2], m2 = Mrow[i2];
  float m = fmaxf(m1, m2);
  float w1 = __builtin_amdgcn_exp2f(m1 - m);
  float w2 = __builtin_amdgcn_exp2f(m2 - m);
  float inv = 1.f / (l1*w1 + l2*w2);
  const short* a1 = Pacc + (size_t)i1*64 + d0;
  const short* a2 = Pacc + (size_t)i2*64 + d0;
  short* ob = Out + ((size_t)(b*NS + qb*128 + q))*NE + h*ND + d0;
  #pragma unroll
  for (int u=0; u<4; ++u){
    s16x8 v1 = *(const s16x8*)(a1 + u*8);
    s16x8 v2 = *(const s16x8*)(a2 + u*8);
    s16x8 o;
    #pragma unroll
    for (int e=0; e<8; ++e)
      o[e] = f2bf((bf2f(v1[e])*w1 + bf2f(v2[e])*w2) * inv);
    *(s16x8*)(ob + u*8) = o;
  }
}

extern "C" void kernel_launch(void* const* d_in, const int* in_sizes, int n_in,
                              void* d_out, int out_size, void* d_ws, size_t ws_size,
                              hipStream_t stream)
{
  const float* x     = (const float*)d_in[0];
  const float* w_qkv = (const float*)d_in[1];
  const float* b_qkv = (const float*)d_in[2];
  const float* w_o   = (const float*)d_in[3];
  const float* b_o   = (const float*)d_in[4];
  char* ws = (char*)d_ws;
  const size_t MB = 1u << 20;
  short* Xb    = (short*)(ws);            // 8 MB (attn-combined output reuses this)
  short* Wqkvt = (short*)(ws + 8*MB);     // 6 MB
  short* Wot   = (short*)(ws + 14*MB);    // 2 MB
  short* QKV   = (short*)(ws + 16*MB);    // 24 MB (dead after k_prep; partials alias it)
  short* Pacc  = (short*)(ws + 16*MB);    // 16 MB  [1024][128][64] bf16
  float* Lrow  = (float*)(ws + 32*MB);    // 512 KB [1024][128]
  float* Mrow  = (float*)(ws + 33*MB);    // 512 KB
  short* Qrp   = (short*)(ws + 40*MB);    // 8 MB
  short* Krp   = (short*)(ws + 48*MB);    // 8 MB
  short* Vtp   = (short*)(ws + 56*MB);    // 8 MB  (total 64 MB)

  k_pre<<<8192, 256, 0, stream>>>(x, w_qkv, w_o, Xb, Wqkvt, Wot);
  k_gemm<0><<<768, 256, 0, stream>>>(Xb, Wqkvt, b_qkv, QKV, nullptr, NB*NS, N3, NE);
  k_prep<<<NB*NH*(NS/64), 256, 0, stream>>>(QKV, Qrp, Krp, Vtp);
  k_attn<<<1024, 256, 0, stream>>>(Qrp, Krp, Vtp, Pacc, Lrow, Mrow);
  k_comb<<<512, 256, 0, stream>>>(Pacc, Lrow, Mrow, Xb);
  k_gemm<1><<<256, 256, 0, stream>>>(Xb, Wot, b_o, nullptr, (float*)d_out, NB*NS, NE, NE);
}

// Round 20
// 117.264 us; speedup vs baseline: 1.0365x; 1.0365x over previous
//
#include <hip/hip_runtime.h>
#include <hip/hip_bf16.h>
#include <stdint.h>

#define NB 2
#define NS 2048
#define NE 1024
#define NH 16
#define ND 64
#define N3 3072

typedef __attribute__((ext_vector_type(8))) short s16x8;
typedef __attribute__((ext_vector_type(4))) short s16x4;
typedef __attribute__((ext_vector_type(4))) float f32x4;
typedef __attribute__((ext_vector_type(16))) float f32x16;
typedef __attribute__((ext_vector_type(2))) unsigned int u32x2;
typedef __attribute__((ext_vector_type(4))) unsigned int u32x4;

__device__ __forceinline__ float bf2f(short u){
  union { unsigned int i; float f; } v; v.i = ((unsigned int)(unsigned short)u) << 16; return v.f;
}
__device__ __forceinline__ short f2bf(float f){
  union { __hip_bfloat16 h; short s; } v; v.h = __float2bfloat16(f); return v.s;
}
__device__ __forceinline__ f32x4 mfma16(s16x8 a, s16x8 b, f32x4 c){
  return __builtin_amdgcn_mfma_f32_16x16x32_bf16(a, b, c, 0, 0, 0);
}
__device__ __forceinline__ f32x16 mfma32(s16x8 a, s16x8 b, f32x16 c){
  return __builtin_amdgcn_mfma_f32_32x32x16_bf16(a, b, c, 0, 0, 0);
}
__device__ __forceinline__ void load_lds16(const void* g, void* l){
  __builtin_amdgcn_global_load_lds(
      (const __attribute__((address_space(1))) unsigned int*)g,
      (__attribute__((address_space(3))) unsigned int*)l, 16, 0, 0);
}
__device__ __forceinline__ unsigned int cvtpk_bf16(float lo, float hi){
  unsigned int d;
  asm("v_cvt_pk_bf16_f32 %0, %1, %2" : "=v"(d) : "v"(lo), "v"(hi));
  return d;
}
// 64-lane reductions via permlane32 swap (VALU, no LDS pipe)
__device__ __forceinline__ float redmax64(float v){
  u32x2 b = __builtin_amdgcn_permlane32_swap(__float_as_uint(v), __float_as_uint(v), false, false);
  return fmaxf(__uint_as_float(b[0]), __uint_as_float(b[1]));
}
__device__ __forceinline__ float redsum64(float v){
  u32x2 b = __builtin_amdgcn_permlane32_swap(__float_as_uint(v), __float_as_uint(v), false, false);
  return __uint_as_float(b[0]) + __uint_as_float(b[1]);
}

// ---------------- merged pre-pass: x->bf16  +  w_qkv^T->bf16  +  w_o^T->bf16 ----------------
__global__ __launch_bounds__(256) void k_pre(const float* __restrict__ x,
    const float* __restrict__ w_qkv, const float* __restrict__ w_o,
    short* __restrict__ Xb, short* __restrict__ Wqkvt, short* __restrict__ Wot)
{
  __shared__ float t[32][33];
  const int bid = blockIdx.x, tid = threadIdx.x;
  if (bid < 4096){
    int i = bid * 256 + tid;
    float4 v = ((const float4*)x)[i];
    s16x4 o = { f2bf(v.x), f2bf(v.y), f2bf(v.z), f2bf(v.w) };
    *(s16x4*)(Xb + (size_t)i*4) = o;
    return;
  }
  const float* in; short* out; int R, C, tile;
  if (bid < 7168){ in = w_qkv; out = Wqkvt; R = NE; C = N3; tile = bid - 4096; }
  else           { in = w_o;   out = Wot;   R = NE; C = NE; tile = bid - 7168; }
  const int tc = C >> 5;
  int c0 = (tile % tc) * 32, r0 = (tile / tc) * 32;
  int tx = tid & 31, ty = tid >> 5;
  #pragma unroll
  for (int i=0;i<4;++i){
    int r = r0 + ty + i*8;
    t[ty + i*8][tx] = in[(size_t)r*C + c0 + tx];
  }
  __syncthreads();
  #pragma unroll
  for (int i=0;i<4;++i){
    int cc = c0 + ty + i*8;
    out[(size_t)cc*R + r0 + tx] = f2bf(t[tx][ty + i*8]);
  }
}

// ---------------- bf16 GEMM: C[M][N] = A[M][K] * Bt[N][K]^T + bias ----------------
// Double-buffered counted-vmcnt pipeline; XCD-aware column-major 1D chunking.
template<int OUTF32>
__global__ __launch_bounds__(256) void k_gemm(const short* __restrict__ A,
    const short* __restrict__ Bt, const float* __restrict__ bias,
    short* __restrict__ outB, float* __restrict__ outF, int M, int N, int K)
{
  __shared__ short lds[2][128*64*2];  // 64 KB: per buf, A tile [128][64] then B tile
  const int tid = threadIdx.x;
  const int lane = tid & 63, w = tid >> 6;
  const int g = lane >> 4, c = lane & 15;
  const int wm = (w >> 1) * 64, wn = (w & 1) * 64;
  const int T = gridDim.x;                 // total tiles, divisible by 8
  const int chunk = T >> 3;
  const int tile = (blockIdx.x & 7) * chunk + (blockIdx.x >> 3);
  const int tm = tile & 31;                // M/128 = 32 always here
  const int tn = tile >> 5;
  const int bm = tm * 128, bn = tn * 128;

  f32x4 acc[4][4];
  #pragma unroll
  for (int i=0;i<4;++i)
    #pragma unroll
    for (int j=0;j<4;++j) acc[i][j] = (f32x4){0.f,0.f,0.f,0.f};

  auto STAGE = [&](int kt, int bsel){
    #pragma unroll
    for (int i = 0; i < 8; ++i){
      const int seg   = w*8 + i;          // 0..31 ; segs 0-15 = A, 16-31 = B
      const int chunkc = seg*64 + lane;   // 16-byte units
      const int local = chunkc & 1023;
      const int row = local >> 3, kc = local & 7;
      const short* base = (chunkc < 1024)
        ? (A  + (size_t)(bm + row) * K + kt*64)
        : (Bt + (size_t)(bn + row) * K + kt*64);
      const char* gaddr = (const char*)base + ((kc*16) ^ ((row & 7) << 4));
      load_lds16(gaddr, (char*)&lds[bsel][0] + seg*1024);
    }
  };

  const int nkt = K >> 6;
  STAGE(0, 0);
  for (int kt = 0; kt < nkt; ++kt){
    const int cur = kt & 1;
    if (kt + 1 < nkt){
      STAGE(kt + 1, cur ^ 1);
      asm volatile("s_waitcnt vmcnt(8)" ::: "memory");  // stage(kt) retired, kt+1 in flight
    } else {
      asm volatile("s_waitcnt vmcnt(0)" ::: "memory");
    }
    __builtin_amdgcn_s_barrier();           // top: stage(kt) visible to all waves
    __builtin_amdgcn_sched_barrier(0);
    const char* Lc = (const char*)&lds[cur][0];
    #pragma unroll
    for (int kk = 0; kk < 2; ++kk){
      s16x8 af[4], bfr[4];
      #pragma unroll
      for (int mi = 0; mi < 4; ++mi){
        int m = wm + mi*16 + c;
        int kb = (kk*64 + g*16) ^ ((m & 7) << 4);
        af[mi] = *(const s16x8*)(Lc + m*128 + kb);
      }
      #pragma unroll
      for (int ni = 0; ni < 4; ++ni){
        int n = wn + ni*16 + c;
        int kb = (kk*64 + g*16) ^ ((n & 7) << 4);
        bfr[ni] = *(const s16x8*)(Lc + 16384 + n*128 + kb);
      }
      #pragma unroll
      for (int mi = 0; mi < 4; ++mi)
        #pragma unroll
        for (int ni = 0; ni < 4; ++ni)
          acc[mi][ni] = mfma16(af[mi], bfr[ni], acc[mi][ni]);
    }
    __builtin_amdgcn_sched_barrier(0);
    __builtin_amdgcn_s_barrier();           // bottom: all waves done with buf[cur]
  }
  #pragma unroll
  for (int mi = 0; mi < 4; ++mi){
    #pragma unroll
    for (int ni = 0; ni < 4; ++ni){
      int col = bn + wn + ni*16 + c;
      float bv = bias[col];
      #pragma unroll
      for (int j = 0; j < 4; ++j){
        int rrow = bm + wm + mi*16 + g*4 + j;   // C/D: col=lane&15, row=4*(lane>>4)+j
        float v = acc[mi][ni][j] + bv;
        if (OUTF32) outF[(size_t)rrow * N + col] = v;
        else        outB[(size_t)rrow * N + col] = f2bf(v);
      }
    }
  }
}

// ---------------- fused prep: Q/K-RoPE -> Qr,Kr [B,H,S,D]  +  V-transpose -> Vt ----
__global__ void k_prep(const short* __restrict__ qkv, short* __restrict__ Qr,
                       short* __restrict__ Kr, short* __restrict__ Vt){
  __shared__ short t[64][72];
  const int bid = blockIdx.x;                 // B*H*(S/64) = 1024
  const int sb = bid & 31, h = (bid>>5) & 15, b = bid >> 9;
  const int s0 = sb * 64;
  const int tid = threadIdx.x;
  const float LGI = 13.287712379549449f / 32.0f;   // log2(10000)/32
  const float QSC = 0.125f * 1.44269504088896340736f;
  #pragma unroll
  for (int it=0; it<2; ++it){
    int u = it*256 + tid;
    int r = u >> 3, cc = (u & 7) * 8;
    int s = s0 + r;
    size_t src = (size_t)(b*NS + s)*N3 + h*ND + cc;
    size_t dst = ((size_t)(b*NH + h)*NS + s)*ND + cc;
    s16x8 rq = *(const s16x8*)(qkv + src);
    s16x8 rk = *(const s16x8*)(qkv + src + 1024);
    s16x8 oq, ok;
    #pragma unroll
    for (int jp=0; jp<4; ++jp){
      int i = (cc >> 1) + jp;
      float inv = __builtin_amdgcn_exp2f(-(float)i * LGI);
      float ang = (float)s * inv;
      float cs = cosf(ang), sn = sinf(ang);
      float q0 = bf2f(rq[2*jp]), q1 = bf2f(rq[2*jp+1]);
      oq[2*jp]   = f2bf((q0*cs - q1*sn) * QSC);
      oq[2*jp+1] = f2bf((q1*cs + q0*sn) * QSC);
      float k0 = bf2f(rk[2*jp]), k1 = bf2f(rk[2*jp+1]);
      ok[2*jp]   = f2bf(k0*cs - k1*sn);
      ok[2*jp+1] = f2bf(k1*cs + k0*sn);
    }
    *(s16x8*)(Qr + dst) = oq;
    *(s16x8*)(Kr + dst) = ok;
  }
  #pragma unroll
  for (int it=0; it<2; ++it){
    int u = it*256 + tid;
    int r = u >> 3, cc = (u & 7) * 8;
    s16x8 v = *(const s16x8*)(qkv + (size_t)(b*NS + s0 + r)*N3 + 2048 + h*ND + cc);
    *(s16x8*)&t[r][cc] = v;
  }
  __syncthreads();
  #pragma unroll
  for (int it=0; it<2; ++it){
    int u = it*256 + tid;
    int d = u >> 3, sc2 = (u & 7) * 8;
    s16x8 v;
    #pragma unroll
    for (int j=0;j<8;++j) v[j] = t[sc2 + j][d];
    *(s16x8*)(Vt + ((size_t)(b*NH + h)*ND + d)*NS + s0 + sc2) = v;
  }
}

// ---------------- causal flash attention (32x32 MFMA, in-register P, KBLK=128) ----
// R12/R15/R18's replay-proven kernel, byte-for-byte (best measured: 49.6 us).
// Split-K (R19) was a net regression (attn -2.5us, combine +6.7us) -> reverted.
__global__ __launch_bounds__(256) void k_attn(const short* __restrict__ Qr,
    const short* __restrict__ Kr2, const short* __restrict__ Vt,
    short* __restrict__ Obuf)
{
  __shared__ short Kb[2][128*64];             // 32 KB  [k=128][d=64] rows 128B
  __shared__ short Vb[2][64*128];             // 32 KB  [d=64][k=128] rows 256B
  const int tid = threadIdx.x;
  const int lane = tid & 63, w = tid >> 6;
  const int ql = lane & 31, hi = lane >> 5;
  const int bid = blockIdx.x;                 // 512
  const int xcd = bid & 7;
  const int qq  = (bid >> 3) & 31;            // 0..31 within each half
  const int heavy = (bid < 256);
  const int j = qq >> 2;                      // 0..7
  const int qb = heavy ? (15 - j) : j;        // heavy tiles in first half
  const int gid = xcd + 8*(qq & 3);           // 0..31: (b,h), XCD-local (4 groups/XCD)
  const int h = gid & 15;
  const int b = gid >> 4;
  const size_t bh = (size_t)(b*NH + h);
  const short* Qbh = Qr + bh * (NS*ND);
  const short* Kbh = Kr2 + bh * (NS*ND);
  const short* Vbh = Vt + bh * (ND*NS);

  // ---- hoisted per-lane staging sources (pre-swizzled) ----
  const char* pK0[4]; const char* pV0[4];
  #pragma unroll
  for (int i=0;i<4;++i){
    int u = w*256 + i*64 + lane;              // 16B-chunk id 0..1023
    int rk = u >> 3, kck = u & 7;             // K: 128 rows x 8 chunks
    pK0[i] = (const char*)Kbh + rk*128 + ((kck*16) ^ ((rk & 7) << 4));
    int rv = u >> 4, kcv = u & 15;            // V: 64 rows x 16 chunks
    pV0[i] = (const char*)Vbh + (size_t)rv*(NS*2) + ((kcv*16) ^ ((rv & 7) << 4));
  }
  // ---- LDS fragment read offsets (swizzle matches staging) ----
  int roffK[4][4];                            // [fr: k-rowblock][dc: d-col]
  #pragma unroll
  for (int fr=0; fr<4; ++fr)
    #pragma unroll
    for (int dc=0; dc<4; ++dc){
      int row = fr*32 + ql;
      roffK[fr][dc] = row*128 + ((dc*32 + 16*hi) ^ ((row & 7) << 4));
    }
  int roffV[2][8];                            // [fr: d-rowblock][kk: k-col]
  #pragma unroll
  for (int fr=0; fr<2; ++fr)
    #pragma unroll
    for (int kk=0; kk<8; ++kk){
      int row = fr*32 + ql;
      roffV[fr][kk] = row*256 + ((kk*32 + 16*hi) ^ ((row & 7) << 4));
    }

  auto STAGE = [&](int tt, int bsel){
    #pragma unroll
    for (int i=0;i<4;++i){
      load_lds16(pK0[i] + (size_t)tt*16384, (char*)&Kb[bsel][0] + w*4096 + i*1024);
      load_lds16(pV0[i] + (size_t)tt*256,   (char*)&Vb[bsel][0] + w*4096 + i*1024);
    }
  };

  const int q0 = qb*128 + w*32;
  const int qglob = q0 + ql;
  const int qtop = q0 + 31;
  const int nkt = qb + 1;                     // block-uniform (128-k tiles)

  s16x8 qf[4];
  #pragma unroll
  for (int dc=0; dc<4; ++dc)
    qf[dc] = *(const s16x8*)(Qbh + (size_t)(q0 + ql)*ND + dc*16 + 8*hi);
  f32x16 accA, accB;
  #pragma unroll
  for (int r=0;r<16;++r){ accA[r]=0.f; accB[r]=0.f; }
  float mrow = -3.0e38f, lrow = 0.f;

  STAGE(0, 0);
  for (int t = 0; t < nkt; ++t){
    const int cur = t & 1;
    if (t + 1 < nkt){
      STAGE(t + 1, cur ^ 1);
      asm volatile("s_waitcnt vmcnt(8)" ::: "memory");  // stage(t) retired, t+1 in flight
    } else {
      asm volatile("s_waitcnt vmcnt(0)" ::: "memory");
    }
    __builtin_amdgcn_s_barrier();             // top: stage(t) visible to all waves
    __builtin_amdgcn_sched_barrier(0);
    if (t*128 <= qtop){                       // conditional body (uniform barriers)
      const char* Kc = (const char*)&Kb[cur][0];
      const char* Vc = (const char*)&Vb[cur][0];
      // ---- QK^T: S^T[k][q], k-quarters fr=0..3 ----
      f32x16 st[4];
      #pragma unroll
      for (int fr=0; fr<4; ++fr)
        #pragma unroll
        for (int r=0;r<16;++r) st[fr][r]=0.f;
      __builtin_amdgcn_s_setprio(1);
      #pragma unroll
      for (int dc=0; dc<4; ++dc)
        #pragma unroll
        for (int fr=0; fr<4; ++fr){
          s16x8 ka = *(const s16x8*)(Kc + roffK[fr][dc]);
          st[fr] = mfma32(ka, qf[dc], st[fr]);
        }
      __builtin_amdgcn_s_setprio(0);
      // ---- causal mask (only tiles overlapping the wave's diagonal) ----
      if (t*128 + 127 > q0){
        #pragma unroll
        for (int fr=0; fr<4; ++fr)
          #pragma unroll
          for (int r=0; r<16; ++r){
            int kg = t*128 + fr*32 + (r&3) + 8*(r>>2) + 4*hi;
            if (kg > qglob) st[fr][r] = -3.0e38f;
          }
      }
      // ---- online softmax (exp2 domain; q = lane&31 lane-local) ----
      float mm[8];
      #pragma unroll
      for (int r=0; r<8; ++r)
        mm[r] = fmaxf(fmaxf(st[0][r], st[0][r+8]), fmaxf(st[1][r], st[1][r+8]));
      #pragma unroll
      for (int r=0; r<8; ++r)
        mm[r] = fmaxf(mm[r], fmaxf(fmaxf(st[2][r], st[2][r+8]),
                                   fmaxf(st[3][r], st[3][r+8])));
      float tm = fmaxf(fmaxf(fmaxf(mm[0],mm[1]), fmaxf(mm[2],mm[3])),
                       fmaxf(fmaxf(mm[4],mm[5]), fmaxf(mm[6],mm[7])));
      tm = redmax64(tm);
      float mn = fmaxf(mrow, tm);
      #pragma unroll
      for (int fr=0; fr<4; ++fr)
        #pragma unroll
        for (int r=0; r<16; ++r)
          st[fr][r] = __builtin_amdgcn_exp2f(st[fr][r] - mn);
      float ss[8];
      #pragma unroll
      for (int r=0; r<8; ++r)
        ss[r] = ((st[0][r] + st[0][r+8]) + (st[1][r] + st[1][r+8]))
              + ((st[2][r] + st[2][r+8]) + (st[3][r] + st[3][r+8]));
      float tl = ((ss[0]+ss[1]) + (ss[2]+ss[3])) + ((ss[4]+ss[5]) + (ss[6]+ss[7]));
      tl = redsum64(tl);
      float alpha = __builtin_amdgcn_exp2f(mrow - mn);
      lrow = lrow*alpha + tl;
      mrow = mn;
      #pragma unroll
      for (int r=0; r<16; ++r){ accA[r] *= alpha; accB[r] *= alpha; }
      // ---- P -> PV B-fragments, fully in-register (cvt_pk + permlane32_swap) ----
      s16x8 pa[8];
      #pragma unroll
      for (int kk=0; kk<8; ++kk){
        const int fr = kk >> 1, m = kk & 1;
        unsigned int P0 = cvtpk_bf16(st[fr][8*m+0], st[fr][8*m+1]);
        unsigned int P1 = cvtpk_bf16(st[fr][8*m+2], st[fr][8*m+3]);
        unsigned int P2 = cvtpk_bf16(st[fr][8*m+4], st[fr][8*m+5]);
        unsigned int P3 = cvtpk_bf16(st[fr][8*m+6], st[fr][8*m+7]);
        u32x2 s02 = __builtin_amdgcn_permlane32_swap(P0, P2, false, false);
        u32x2 s13 = __builtin_amdgcn_permlane32_swap(P1, P3, false, false);
        u32x4 pd = { s02[0], s13[0], s02[1], s13[1] };
        pa[kk] = *(s16x8*)&pd;
      }
      // ---- PV: O^T[d][q] += V^T[d][k] * P[k][q] ----
      __builtin_amdgcn_s_setprio(1);
      #pragma unroll
      for (int kk=0; kk<8; ++kk){
        s16x8 va  = *(const s16x8*)(Vc + roffV[0][kk]);
        s16x8 vb2 = *(const s16x8*)(Vc + roffV[1][kk]);
        accA = mfma32(va,  pa[kk], accA);
        accB = mfma32(vb2, pa[kk], accB);
      }
      __builtin_amdgcn_s_setprio(0);
    }
    __builtin_amdgcn_sched_barrier(0);
    __builtin_amdgcn_s_barrier();             // bottom: all waves done with buf[cur]
  }
  const float invl = 1.f / lrow;              // lane-local (q = lane&31)
  short* obase = Obuf + (size_t)(b*NS + q0 + ql)*NE + h*ND;
  #pragma unroll
  for (int f=0; f<4; ++f){
    s16x4 oa = { f2bf(accA[4*f+0]*invl), f2bf(accA[4*f+1]*invl),
                 f2bf(accA[4*f+2]*invl), f2bf(accA[4*f+3]*invl) };
    *(s16x4*)(obase + 8*f + 4*hi) = oa;
    s16x4 ob = { f2bf(accB[4*f+0]*invl), f2bf(accB[4*f+1]*invl),
                 f2bf(accB[4*f+2]*invl), f2bf(accB[4*f+3]*invl) };
    *(s16x4*)(obase + 32 + 8*f + 4*hi) = ob;
  }
}

extern "C" void kernel_launch(void* const* d_in, const int* in_sizes, int n_in,
                              void* d_out, int out_size, void* d_ws, size_t ws_size,
                              hipStream_t stream)
{
  const float* x     = (const float*)d_in[0];
  const float* w_qkv = (const float*)d_in[1];
  const float* b_qkv = (const float*)d_in[2];
  const float* w_o   = (const float*)d_in[3];
  const float* b_o   = (const float*)d_in[4];
  char* ws = (char*)d_ws;
  const size_t MB = 1u << 20;
  short* Xb    = (short*)(ws);            // 8 MB (reused as Obuf after GEMM1)
  short* Wqkvt = (short*)(ws + 8*MB);     // 6 MB
  short* Wot   = (short*)(ws + 14*MB);    // 2 MB
  short* QKV   = (short*)(ws + 16*MB);    // 24 MB
  short* Qrp   = (short*)(ws + 40*MB);    // 8 MB
  short* Krp   = (short*)(ws + 48*MB);    // 8 MB
  short* Vtp   = (short*)(ws + 56*MB);    // 8 MB  (total 64 MB)

  k_pre<<<8192, 256, 0, stream>>>(x, w_qkv, w_o, Xb, Wqkvt, Wot);
  k_gemm<0><<<768, 256, 0, stream>>>(Xb, Wqkvt, b_qkv, QKV, nullptr, NB*NS, N3, NE);
  k_prep<<<NB*NH*(NS/64), 256, 0, stream>>>(QKV, Qrp, Krp, Vtp);
  k_attn<<<NB*NH*16, 256, 0, stream>>>(Qrp, Krp, Vtp, Xb);
  k_gemm<1><<<256, 256, 0, stream>>>(Xb, Wot, b_o, nullptr, (float*)d_out, NB*NS, NE, NE);
}